// Round 3
// baseline (282.609 us; speedup 1.0000x reference)
//
#include <hip/hip_runtime.h>
#include <math.h>

// Fused AntiAliasActivation: up2 (12-tap polyphase) -> snake -> down2 (12-tap)
// x: (B=16, C=512, T=4096) fp32, out: same shape.
//
// R5: register-blocked like R4 (one block/row, W=16 outputs/thread,
// LDS-free) but with the two R4 regressions fixed:
//  1. __launch_bounds__(NT, 2): R4's bare (256) made the compiler target
//     8 waves/EU (<=64 VGPR) and SPILL the ~90-float live set to scratch
//     (VGPR_Count=44, occupancy capped 45%, VALUBusy 27%). Cap at 128.
//  2. Rolling accumulation: each activation pair (ev,ov) is consumed
//     immediately into the <=6 acc[] entries it feeds; e[21]/o_[21]
//     arrays never materialize. Live set ~90 floats -> no spill.
//
// Phase-plane formulation (verified R3/R4):
//   E[s] = act( 2*sum_m x[clamp(s-3+m)]*u[11-2m] )   (yact[2s])
//   O[s] = act( 2*sum_m x[clamp(s-2+m)]*u[10-2m] )   (yact[2s+1])
//   out[o] = sum_m E[o-2+m]*d[2m+1] + sum_m O[o-3+m]*d[2m]
//   act(y) = y + rb*sin(y*ea)^2
// Index map per thread (o0 = 16*t): f[j] = x[o0-8+j] (j=0..31, f[29..31]
// pad); activation i=0..20 gives ev=E[o0-2+i], ov=O[o0-3+i], window
// f[i+3..i+8]; contribution of i to acc[r]: r in [i-5,i]&[0,15], taps
// d[2(i-r)+1] (E) and d[2(i-r)] (O).
// Down-conv pad clamp: lo thread (t=0): e[0..1],o_[0..2] -> E[0] (=ev at
// i=2): skip i<2 contributions, patch at i=2, ov:=ev. hi thread (t=255):
// e[18..20],o_[19..20] -> O[T-1] (=ov at i=18): override ev/ov i>=18.

#define T_LEN 4096
#define NT    256
#define W     16                 // outputs per thread; NT*W == T_LEN

__global__ __launch_bounds__(NT, 2) void aa_act_kernel(
    const float* __restrict__ x,
    const float* __restrict__ alpha,
    const float* __restrict__ beta,
    const float* __restrict__ upf,
    const float* __restrict__ downf,
    float* __restrict__ out,
    int C)
{
    const int t   = threadIdx.x;
    const int row = blockIdx.x;
    const int c   = row % C;
    const int o0  = t * W;

    const float* __restrict__ xr = x + (size_t)row * T_LEN;
    float* __restrict__ outr     = out + (size_t)row * T_LEN;

    // Uniform filter taps. Prescale up-filter by 2 (UP factor) — exact.
    float ue[6], uo[6], d[12];
#pragma unroll
    for (int m = 0; m < 6; ++m) {
        ue[m] = 2.0f * upf[11 - 2 * m];
        uo[m] = 2.0f * upf[10 - 2 * m];
    }
#pragma unroll
    for (int i = 0; i < 12; ++i) d[i] = downf[i];

    const float ea = __expf(alpha[c]);
    const float rb = 1.0f / (__expf(beta[c]) + 1e-9f);

    const bool lo = (t == 0);
    const bool hi = (t == NT - 1);

    // ---- x[o0-8 .. o0+23] -> f[0..31] (16B-aligned float4 loads) ----
    float f[32];
    if (!lo && !hi) {
        const float4* p = (const float4*)(xr + o0 - 8);
#pragma unroll
        for (int i = 0; i < 8; ++i) ((float4*)f)[i] = p[i];
    } else {
        // row-edge threads: scalar clamped loads (up-conv edge pad)
#pragma unroll
        for (int i = 0; i < 32; ++i)
            f[i] = xr[min(max(o0 - 8 + i, 0), T_LEN - 1)];
    }

    float acc[W];
#pragma unroll
    for (int r = 0; r < W; ++r) acc[r] = 0.0f;

    float Rv = 0.0f;   // O[T-1] capture (hi lane only)

#pragma unroll
    for (int i = 0; i < 21; ++i) {
        // activation pair at rolling index i
        float ye = f[i + 3] * ue[0];
        ye = fmaf(f[i + 4], ue[1], ye);
        ye = fmaf(f[i + 5], ue[2], ye);
        ye = fmaf(f[i + 6], ue[3], ye);
        ye = fmaf(f[i + 7], ue[4], ye);
        ye = fmaf(f[i + 8], ue[5], ye);
        float yo = f[i + 3] * uo[0];
        yo = fmaf(f[i + 4], uo[1], yo);
        yo = fmaf(f[i + 5], uo[2], yo);
        yo = fmaf(f[i + 6], uo[3], yo);
        yo = fmaf(f[i + 7], uo[4], yo);
        yo = fmaf(f[i + 8], uo[5], yo);
        float se = __sinf(ye * ea);
        float so = __sinf(yo * ea);
        float ev = fmaf(rb * se, se, ye);
        float ov = fmaf(rb * so, so, yo);

        // ---- down-conv pad-clamp overrides (row edges) ----
        if (i == 18) {
            if (hi) { Rv = ov; ev = ov; }          // e[18] := O[T-1]
        }
        if (i >= 19) {
            if (hi) { ev = Rv; ov = Rv; }          // e/o[19..20] := O[T-1]
        }
        if (i == 2) {
            if (lo) {
                // ev == E[0]; patch the skipped i=0,1 contributions
                acc[0] = fmaf(ev, d[0] + d[1] + d[2] + d[3], acc[0]);
                acc[1] = fmaf(ev, d[0] + d[1], acc[1]);
                ov = ev;                            // o_[2] := E[0]
            }
        }

        // ---- consume into accumulators: r in [i-5, i] & [0, 15] ----
        const int rlo = (i - 5 > 0) ? (i - 5) : 0;
        const int rhi = (i < W - 1) ? i : (W - 1);
        if (i < 2) {
            if (!lo) {
#pragma unroll
                for (int r = rlo; r <= rhi; ++r)
                    acc[r] = fmaf(ev, d[2 * (i - r) + 1],
                             fmaf(ov, d[2 * (i - r)], acc[r]));
            }
        } else {
#pragma unroll
            for (int r = rlo; r <= rhi; ++r)
                acc[r] = fmaf(ev, d[2 * (i - r) + 1],
                         fmaf(ov, d[2 * (i - r)], acc[r]));
        }
    }

#pragma unroll
    for (int i = 0; i < 4; ++i)
        ((float4*)(outr + o0))[i] = *(float4*)(acc + 4 * i);
}

extern "C" void kernel_launch(void* const* d_in, const int* in_sizes, int n_in,
                              void* d_out, int out_size, void* d_ws, size_t ws_size,
                              hipStream_t stream) {
    const float* x     = (const float*)d_in[0];
    const float* alpha = (const float*)d_in[1];
    const float* beta  = (const float*)d_in[2];
    const float* upf   = (const float*)d_in[3];
    const float* downf = (const float*)d_in[4];
    float* out = (float*)d_out;

    const int C    = in_sizes[1];             // 512
    const int rows = in_sizes[0] / T_LEN;     // B*C = 8192

    dim3 grid(rows), block(NT);
    hipLaunchKernelGGL(aa_act_kernel, grid, block, 0, stream,
                       x, alpha, beta, upf, downf, out, C);
}

// Round 5
// 241.703 us; speedup vs baseline: 1.1692x; 1.1692x over previous
//
#include <hip/hip_runtime.h>
#include <math.h>

// Fused AntiAliasActivation: up2 (12-tap polyphase) -> snake -> down2 (12-tap)
// x: (B=16, C=512, T=4096) fp32, out: same shape.
//
// R6: R5's rolling-accumulation structure (hardware-verified correct)
// with the scratch-spill root cause fixed. R4/R5 reported VGPR_Count=44
// + ~105MB of extra WRITE_SIZE: the private arrays f[]/acc[] were
// accessed via type-punned casts (((float4*)f)[i], *(float4*)(acc+4*i)),
// which defeats LLVM SROA -> the allocas stayed in SCRATCH, and
// __launch_bounds__ couldn't help because no regalloc fight ever
// happened. R6 keeps every private-array access scalar with
// compile-time indices (float4 loads decomposed by component, stores
// composed via make_float4) so f/acc promote to VGPRs.
//
// Phase-plane formulation (verified R3/R4/R5):
//   E[s] = act( 2*sum_m x[clamp(s-3+m)]*u[11-2m] )   (yact[2s])
//   O[s] = act( 2*sum_m x[clamp(s-2+m)]*u[10-2m] )   (yact[2s+1])
//   out[o] = sum_m E[o-2+m]*d[2m+1] + sum_m O[o-3+m]*d[2m]
//   act(y) = y + rb*sin(y*ea)^2
// Per thread (o0 = 16*t): f[j] = x[clamp(o0-8+j)], j=0..31; activation
// i=0..20 gives ev=E[o0-2+i], ov=O[o0-3+i] from window f[i+3..i+8];
// contribution of i to acc[r]: r in [i-5,i]&[0,15], taps d[2(i-r)+1]
// (E) and d[2(i-r)] (O).
// Down-conv pad clamp: lo thread (t=0): skip i<2, patch at i=2 with
// E[0]; hi thread (t=255): override ev/ov with O[T-1] from i=18.

#define T_LEN 4096
#define NT    256
#define W     16                 // outputs per thread; NT*W == T_LEN

__global__ __launch_bounds__(NT, 2) void aa_act_kernel(
    const float* __restrict__ x,
    const float* __restrict__ alpha,
    const float* __restrict__ beta,
    const float* __restrict__ upf,
    const float* __restrict__ downf,
    float* __restrict__ out,
    int C)
{
    const int t   = threadIdx.x;
    const int row = blockIdx.x;
    const int c   = row % C;
    const int o0  = t * W;

    const float* __restrict__ xr = x + (size_t)row * T_LEN;
    float* __restrict__ outr     = out + (size_t)row * T_LEN;

    // Uniform filter taps. Prescale up-filter by 2 (UP factor) — exact.
    float ue[6], uo[6], d[12];
#pragma unroll
    for (int m = 0; m < 6; ++m) {
        ue[m] = 2.0f * upf[11 - 2 * m];
        uo[m] = 2.0f * upf[10 - 2 * m];
    }
#pragma unroll
    for (int i = 0; i < 12; ++i) d[i] = downf[i];

    const float ea = __expf(alpha[c]);
    const float rb = 1.0f / (__expf(beta[c]) + 1e-9f);

    const bool lo = (t == 0);
    const bool hi = (t == NT - 1);

    // ---- x[o0-8 .. o0+23] -> f[0..31], SROA-friendly ----
    float f[32];
    if (!lo && !hi) {
        const float4* p = (const float4*)(xr + o0 - 8);  // global: cast ok
        float4 v0 = p[0], v1 = p[1], v2 = p[2], v3 = p[3];
        float4 v4 = p[4], v5 = p[5], v6 = p[6], v7 = p[7];
        f[ 0]=v0.x; f[ 1]=v0.y; f[ 2]=v0.z; f[ 3]=v0.w;
        f[ 4]=v1.x; f[ 5]=v1.y; f[ 6]=v1.z; f[ 7]=v1.w;
        f[ 8]=v2.x; f[ 9]=v2.y; f[10]=v2.z; f[11]=v2.w;
        f[12]=v3.x; f[13]=v3.y; f[14]=v3.z; f[15]=v3.w;
        f[16]=v4.x; f[17]=v4.y; f[18]=v4.z; f[19]=v4.w;
        f[20]=v5.x; f[21]=v5.y; f[22]=v5.z; f[23]=v5.w;
        f[24]=v6.x; f[25]=v6.y; f[26]=v6.z; f[27]=v6.w;
        f[28]=v7.x; f[29]=v7.y; f[30]=v7.z; f[31]=v7.w;
    } else {
        // row-edge threads: scalar clamped loads (up-conv edge pad)
#pragma unroll
        for (int i = 0; i < 32; ++i)
            f[i] = xr[min(max(o0 - 8 + i, 0), T_LEN - 1)];
    }

    float acc[W];
#pragma unroll
    for (int r = 0; r < W; ++r) acc[r] = 0.0f;

    float Rv = 0.0f;   // O[T-1] capture (hi lane only)

#pragma unroll
    for (int i = 0; i < 21; ++i) {
        // activation pair at rolling index i
        float ye = f[i + 3] * ue[0];
        ye = fmaf(f[i + 4], ue[1], ye);
        ye = fmaf(f[i + 5], ue[2], ye);
        ye = fmaf(f[i + 6], ue[3], ye);
        ye = fmaf(f[i + 7], ue[4], ye);
        ye = fmaf(f[i + 8], ue[5], ye);
        float yo = f[i + 3] * uo[0];
        yo = fmaf(f[i + 4], uo[1], yo);
        yo = fmaf(f[i + 5], uo[2], yo);
        yo = fmaf(f[i + 6], uo[3], yo);
        yo = fmaf(f[i + 7], uo[4], yo);
        yo = fmaf(f[i + 8], uo[5], yo);
        float se = __sinf(ye * ea);
        float so = __sinf(yo * ea);
        float ev = fmaf(rb * se, se, ye);
        float ov = fmaf(rb * so, so, yo);

        // ---- down-conv pad-clamp overrides (row edges) ----
        if (i == 18) {
            if (hi) { Rv = ov; ev = ov; }          // e[18] := O[T-1]
        }
        if (i >= 19) {
            if (hi) { ev = Rv; ov = Rv; }          // e/o[19..20] := O[T-1]
        }
        if (i == 2) {
            if (lo) {
                // ev == E[0]; patch the skipped i=0,1 contributions
                acc[0] = fmaf(ev, d[0] + d[1] + d[2] + d[3], acc[0]);
                acc[1] = fmaf(ev, d[0] + d[1], acc[1]);
                ov = ev;                            // o_[2] := E[0]
            }
        }

        // ---- consume into accumulators: r in [i-5, i] & [0, 15] ----
        const int rlo = (i - 5 > 0) ? (i - 5) : 0;
        const int rhi = (i < W - 1) ? i : (W - 1);
        if (i < 2) {
            if (!lo) {
#pragma unroll
                for (int r = rlo; r <= rhi; ++r)
                    acc[r] = fmaf(ev, d[2 * (i - r) + 1],
                             fmaf(ov, d[2 * (i - r)], acc[r]));
            }
        } else {
#pragma unroll
            for (int r = rlo; r <= rhi; ++r)
                acc[r] = fmaf(ev, d[2 * (i - r) + 1],
                         fmaf(ov, d[2 * (i - r)], acc[r]));
        }
    }

    // ---- store: compose float4 from components (SROA-friendly) ----
    float4* po = (float4*)(outr + o0);           // global: cast ok
    po[0] = make_float4(acc[ 0], acc[ 1], acc[ 2], acc[ 3]);
    po[1] = make_float4(acc[ 4], acc[ 5], acc[ 6], acc[ 7]);
    po[2] = make_float4(acc[ 8], acc[ 9], acc[10], acc[11]);
    po[3] = make_float4(acc[12], acc[13], acc[14], acc[15]);
}

extern "C" void kernel_launch(void* const* d_in, const int* in_sizes, int n_in,
                              void* d_out, int out_size, void* d_ws, size_t ws_size,
                              hipStream_t stream) {
    const float* x     = (const float*)d_in[0];
    const float* alpha = (const float*)d_in[1];
    const float* beta  = (const float*)d_in[2];
    const float* upf   = (const float*)d_in[3];
    const float* downf = (const float*)d_in[4];
    float* out = (float*)d_out;

    const int C    = in_sizes[1];             // 512
    const int rows = in_sizes[0] / T_LEN;     // B*C = 8192

    dim3 grid(rows), block(NT);
    hipLaunchKernelGGL(aa_act_kernel, grid, block, 0, stream,
                       x, alpha, beta, upf, downf, out, C);
}